// Round 1
// baseline (2702.839 us; speedup 1.0000x reference)
//
#include <hip/hip_runtime.h>
#include <cstddef>

constexpr int NB   = 512;  // batch
constexpr int ND   = 512;  // dim
constexpr int NL   = 32;   // context length
constexpr int NHW  = 196;  // knowledge spatial
constexpr int NK   = 8;    // history slots
constexpr int NSTEP = 4;

// =====================================================================
// Generic tiled fp32 GEMM:  C = act(concat(A1,A2) @ B(^T) + bias)
//  A1: (M,k1) stride lda1; A2: (M,K-k1) stride lda2 (row-major)
//  BT=true : Bw is (N,K) row-major  -> C = A @ Bw^T   (torch Linear)
//  BT=false: Bw is (K,N) row-major  -> C = A @ Bw
//  Tile 32(M) x 64(N) x 16(K); 256 threads; 2x4 micro-tile.
//  Requires: M%32==0, N%64==0, K%16==0, k1%16==0.
// =====================================================================
template<bool BT, int ACT>   // ACT: 0 none, 1 elu
__global__ __launch_bounds__(256) void gemm_k(
    const float* __restrict__ A1, int lda1, int k1,
    const float* __restrict__ A2, int lda2,
    const float* __restrict__ Bw,
    const float* __restrict__ bias,
    float* __restrict__ C, int N, int K)
{
    __shared__ float As[16][32];
    __shared__ float Bs[16][64];
    const int t  = threadIdx.x;
    const int m0 = blockIdx.y * 32;
    const int n0 = blockIdx.x * 64;
    const int tx = t & 15, ty = t >> 4;
    float acc[2][4] = {{0.f,0.f,0.f,0.f},{0.f,0.f,0.f,0.f}};

    for (int kt = 0; kt < K; kt += 16) {
        // ---- stage A tile (32 rows x 16 k), float2 per thread ----
        {
            const int r = t >> 3, kk2 = (t & 7) * 2;
            const int kc = kt + kk2;
            float2 av;
            if (kc < k1) av = *(const float2*)(A1 + (size_t)(m0 + r) * lda1 + kc);
            else         av = *(const float2*)(A2 + (size_t)(m0 + r) * lda2 + (kc - k1));
            As[kk2][r] = av.x; As[kk2 + 1][r] = av.y;
        }
        // ---- stage B tile (16 k x 64 n) ----
        if (BT) {
            const int n = t >> 2, kk4 = (t & 3) * 4;
            float4 bv = *(const float4*)(Bw + (size_t)(n0 + n) * K + kt + kk4);
            Bs[kk4 + 0][n] = bv.x; Bs[kk4 + 1][n] = bv.y;
            Bs[kk4 + 2][n] = bv.z; Bs[kk4 + 3][n] = bv.w;
        } else {
            const int kk = t >> 4, n4 = (t & 15) * 4;
            *(float4*)&Bs[kk][n4] = *(const float4*)(Bw + (size_t)(kt + kk) * N + n0 + n4);
        }
        __syncthreads();
        #pragma unroll
        for (int kk = 0; kk < 16; ++kk) {
            float2 a = *(const float2*)&As[kk][ty * 2];
            float4 b = *(const float4*)&Bs[kk][tx * 4];
            acc[0][0] += a.x * b.x; acc[0][1] += a.x * b.y;
            acc[0][2] += a.x * b.z; acc[0][3] += a.x * b.w;
            acc[1][0] += a.y * b.x; acc[1][1] += a.y * b.y;
            acc[1][2] += a.y * b.z; acc[1][3] += a.y * b.w;
        }
        __syncthreads();
    }
    #pragma unroll
    for (int i = 0; i < 2; ++i) {
        const int m = m0 + ty * 2 + i;
        float o[4];
        #pragma unroll
        for (int j = 0; j < 4; ++j) {
            float x = acc[i][j];
            if (bias) x += bias[n0 + tx * 4 + j];
            if (ACT == 1) x = (x > 0.f) ? x : (expf(x) - 1.f);
            o[j] = x;
        }
        *(float4*)(C + (size_t)m * N + n0 + tx * 4) = make_float4(o[0], o[1], o[2], o[3]);
    }
}

// =====================================================================
// Control attention: scores over L=32, softmax, weighted-sum -> control
// Also emits cw = control*read_attn_w, cwh = control*rm_attn_w.
// (scalar attn bias cancels in softmax)
// One block per batch element.
// =====================================================================
__global__ __launch_bounds__(256) void ctrl_attn_k(
    const float* __restrict__ cqi,        // (B,512)
    const float* __restrict__ context,    // (B,32,512)
    const float* __restrict__ attn_w,     // (512) = ctrl_attn_w
    const float* __restrict__ read_attn_w,// (512)
    const float* __restrict__ rm_attn_w,  // (512)
    float* __restrict__ control,          // out (B,512)
    float* __restrict__ cw,               // out (B,512)
    float* __restrict__ cwh)              // out (B,512)
{
    const int b = blockIdx.x, t = threadIdx.x;
    const int lane = t & 63, w = t >> 6;
    __shared__ float q[ND];
    __shared__ float p[NL];
    const float* ctx = context + (size_t)b * NL * ND;

    for (int d = t; d < ND; d += 256) q[d] = cqi[(size_t)b * ND + d] * attn_w[d];
    __syncthreads();

    for (int l = w; l < NL; l += 4) {
        float s = 0.f;
        const float* row = ctx + (size_t)l * ND;
        #pragma unroll 4
        for (int d = lane; d < ND; d += 64) s += q[d] * row[d];
        #pragma unroll
        for (int o = 32; o; o >>= 1) s += __shfl_down(s, o);
        if (lane == 0) p[l] = s;
    }
    __syncthreads();
    if (t == 0) {
        float mx = p[0];
        for (int l = 1; l < NL; ++l) mx = fmaxf(mx, p[l]);
        float sum = 0.f;
        for (int l = 0; l < NL; ++l) { float e = expf(p[l] - mx); p[l] = e; sum += e; }
        const float inv = 1.f / sum;
        for (int l = 0; l < NL; ++l) p[l] *= inv;
    }
    __syncthreads();
    for (int d = t; d < ND; d += 256) {
        float a = 0.f;
        #pragma unroll 8
        for (int l = 0; l < NL; ++l) a += p[l] * ctx[(size_t)l * ND + d];
        control[(size_t)b * ND + d] = a;
        cw [(size_t)b * ND + d] = a * read_attn_w[d];
        cwh[(size_t)b * ND + d] = a * rm_attn_w[d];
    }
}

// =====================================================================
// KB attention (collapsed): v[j] = mem_p[j]*u[j] + u[j+512];
// s[h] = sum_j kb_proj[b,j,h]*v[j]; softmax over h; read[d] = sum_h p[h]*knowledge[b,d,h]
// One block per batch element.
// =====================================================================
__global__ __launch_bounds__(256) void kb_attn_k(
    const float* __restrict__ kb_proj,   // (B,512,196)
    const float* __restrict__ knowledge, // (B,512,196)
    const float* __restrict__ mem_p,     // (B,512)
    const float* __restrict__ u,         // (B,1024)
    float* __restrict__ readv)           // out (B,512)
{
    const int b = blockIdx.x, t = threadIdx.x;
    const int lane = t & 63, w = t >> 6;
    __shared__ float v[ND];
    __shared__ float p[256];
    __shared__ float red[8];

    for (int d = t; d < ND; d += 256)
        v[d] = mem_p[(size_t)b * ND + d] * u[(size_t)b * 2 * ND + d] + u[(size_t)b * 2 * ND + ND + d];
    __syncthreads();

    const float* kbp = kb_proj + (size_t)b * ND * NHW;
    float val = -INFINITY;
    if (t < NHW) {
        float s0 = 0.f, s1 = 0.f, s2 = 0.f, s3 = 0.f;
        #pragma unroll 4
        for (int k = 0; k < ND; k += 4) {
            s0 += kbp[(size_t)(k + 0) * NHW + t] * v[k + 0];
            s1 += kbp[(size_t)(k + 1) * NHW + t] * v[k + 1];
            s2 += kbp[(size_t)(k + 2) * NHW + t] * v[k + 2];
            s3 += kbp[(size_t)(k + 3) * NHW + t] * v[k + 3];
        }
        val = (s0 + s1) + (s2 + s3);
    }
    // block softmax over 196 (inactive lanes carry -inf / 0)
    float mx = val;
    #pragma unroll
    for (int o = 32; o; o >>= 1) mx = fmaxf(mx, __shfl_xor(mx, o));
    if (lane == 0) red[w] = mx;
    __syncthreads();
    mx = fmaxf(fmaxf(red[0], red[1]), fmaxf(red[2], red[3]));
    float e = (t < NHW) ? expf(val - mx) : 0.f;
    float sm = e;
    #pragma unroll
    for (int o = 32; o; o >>= 1) sm += __shfl_xor(sm, o);
    if (lane == 0) red[4 + w] = sm;
    __syncthreads();
    const float tot = red[4] + red[5] + red[6] + red[7];
    p[t] = e / tot;
    __syncthreads();

    const float* knw = knowledge + (size_t)b * ND * NHW;
    for (int dd = w; dd < ND; dd += 4) {
        const float* row = knw + (size_t)dd * NHW;
        float a = 0.f;
        for (int h = lane; h < NHW; h += 64) a += p[h] * row[h];
        #pragma unroll
        for (int o = 32; o; o >>= 1) a += __shfl_down(a, o);
        if (lane == 0) readv[(size_t)b * ND + dd] = a;
    }
}

// =====================================================================
// History attention (collapsed), K=8 slots. One block per batch element.
// vh[j] = memh[j]*uh[j] + uh[j+512]; s[k] = sum_j hist[b,j,k]*vh[j];
// rvi = softmax_k(s); read_h[d] = sum_k rvi[k]*hist[b,d,k]
// =====================================================================
__global__ __launch_bounds__(256) void hist_attn_k(
    const float* __restrict__ hist,  // (B,512,8)
    const float* __restrict__ memh,  // (B,512)
    const float* __restrict__ uh,    // (B,1024)
    float* __restrict__ rvi,         // out (B,8)
    float* __restrict__ read_h)      // out (B,512)
{
    const int b = blockIdx.x, t = threadIdx.x;
    const int lane = t & 63, w = t >> 6;
    __shared__ float ht[NK][ND];   // transposed history, 16 KB
    __shared__ float vh[ND];
    __shared__ float sred[NK];
    __shared__ float pk[NK];
    const float* hb = hist + (size_t)b * ND * NK;

    for (int dd = t; dd < ND; dd += 256) {
        float4 h0 = *(const float4*)&hb[(size_t)dd * NK];
        float4 h1 = *(const float4*)&hb[(size_t)dd * NK + 4];
        ht[0][dd] = h0.x; ht[1][dd] = h0.y; ht[2][dd] = h0.z; ht[3][dd] = h0.w;
        ht[4][dd] = h1.x; ht[5][dd] = h1.y; ht[6][dd] = h1.z; ht[7][dd] = h1.w;
        vh[dd] = memh[(size_t)b * ND + dd] * uh[(size_t)b * 2 * ND + dd]
               + uh[(size_t)b * 2 * ND + ND + dd];
    }
    __syncthreads();

    for (int k = w; k < NK; k += 4) {
        float s = 0.f;
        #pragma unroll 4
        for (int dd = lane; dd < ND; dd += 64) s += ht[k][dd] * vh[dd];
        #pragma unroll
        for (int o = 32; o; o >>= 1) s += __shfl_down(s, o);
        if (lane == 0) sred[k] = s;
    }
    __syncthreads();
    if (t == 0) {
        float mx = sred[0];
        #pragma unroll
        for (int k = 1; k < NK; ++k) mx = fmaxf(mx, sred[k]);
        float ev[NK]; float sum = 0.f;
        #pragma unroll
        for (int k = 0; k < NK; ++k) { ev[k] = expf(sred[k] - mx); sum += ev[k]; }
        const float inv = 1.f / sum;
        #pragma unroll
        for (int k = 0; k < NK; ++k) { float pv = ev[k] * inv; pk[k] = pv; rvi[(size_t)b * NK + k] = pv; }
    }
    __syncthreads();
    for (int dd = t; dd < ND; dd += 256) {
        float a = 0.f;
        #pragma unroll
        for (int k = 0; k < NK; ++k) a += pk[k] * ht[k][dd];
        read_h[(size_t)b * ND + dd] = a;
    }
}

// =====================================================================
// Per-batch scalars: gkb, gmem (sigmoid of dot-1024), cwv (softmax3 of dots-512)
// =====================================================================
__global__ __launch_bounds__(256) void scalars_k(
    const float* __restrict__ g1a, const float* __restrict__ g1b,
    const float* __restrict__ m1,
    const float* __restrict__ lr_w2,  const float* __restrict__ lr_b2,
    const float* __restrict__ lrh_w2, const float* __restrict__ lrh_b2,
    const float* __restrict__ mix_w2, const float* __restrict__ mix_b2,
    float* __restrict__ gkb, float* __restrict__ gmem, float* __restrict__ cwv)
{
    const int b = blockIdx.x, t = threadIdx.x;
    const int lane = t & 63, w = t >> 6;
    float pa = 0.f, pb = 0.f, p0 = 0.f, p1 = 0.f, p2 = 0.f;
    for (int k = t; k < 2 * ND; k += 256) {
        pa += g1a[(size_t)b * 2 * ND + k] * lr_w2[k];
        pb += g1b[(size_t)b * 2 * ND + k] * lrh_w2[k];
    }
    for (int d = t; d < ND; d += 256) {
        const float m = m1[(size_t)b * ND + d];
        p0 += m * mix_w2[d];
        p1 += m * mix_w2[ND + d];
        p2 += m * mix_w2[2 * ND + d];
    }
    #pragma unroll
    for (int o = 32; o; o >>= 1) {
        pa += __shfl_down(pa, o); pb += __shfl_down(pb, o);
        p0 += __shfl_down(p0, o); p1 += __shfl_down(p1, o); p2 += __shfl_down(p2, o);
    }
    __shared__ float red[4][5];
    if (lane == 0) { red[w][0] = pa; red[w][1] = pb; red[w][2] = p0; red[w][3] = p1; red[w][4] = p2; }
    __syncthreads();
    if (t == 0) {
        float sa = 0.f, sb = 0.f, s0 = 0.f, s1 = 0.f, s2 = 0.f;
        #pragma unroll
        for (int i = 0; i < 4; ++i) { sa += red[i][0]; sb += red[i][1]; s0 += red[i][2]; s1 += red[i][3]; s2 += red[i][4]; }
        gkb[b]  = 1.f / (1.f + expf(-(sa + lr_b2[0])));
        gmem[b] = 1.f / (1.f + expf(-(sb + lrh_b2[0])));
        const float l0 = s0 + mix_b2[0], l1 = s1 + mix_b2[1], l2 = s2 + mix_b2[2];
        const float mx = fmaxf(l0, fmaxf(l1, l2));
        const float e0 = expf(l0 - mx), e1 = expf(l1 - mx), e2 = expf(l2 - mx);
        const float inv = 1.f / (e0 + e1 + e2);
        cwv[(size_t)b * 4 + 0] = e0 * inv;
        cwv[(size_t)b * 4 + 1] = e1 * inv;
        cwv[(size_t)b * 4 + 2] = e2 * inv;
    }
}

// =====================================================================
// State update: W, in-place history update, wts shift, ctx_read
// One block per batch element.
// =====================================================================
__global__ __launch_bounds__(256) void update_k(
    const float* __restrict__ rvi,   // (B,8)
    const float* __restrict__ gkb_,  // (B)
    const float* __restrict__ gmem_, // (B)
    const float* __restrict__ cwv,   // (B,4)
    const float* __restrict__ readv, // (B,512)
    const float* __restrict__ read_h,// (B,512)
    float* __restrict__ hist,        // (B,512,8) in-place
    float* __restrict__ wts,         // (B,8) in-place
    float* __restrict__ ctx_read)    // out (B,512)
{
    const int b = blockIdx.x, t = threadIdx.x;
    __shared__ float wo[NK], Ws[NK];
    const float gk = gkb_[b], gm = gmem_[b];
    if (t < NK) {
        const float w_old = wts[(size_t)b * NK + t];
        wo[t] = w_old;
        Ws[t] = (gm * rvi[(size_t)b * NK + t] + w_old * (1.f - gm)) * gk;
    }
    __syncthreads();
    float Wr[NK];
    #pragma unroll
    for (int k = 0; k < NK; ++k) Wr[k] = Ws[k];
    const float c0 = cwv[(size_t)b * 4 + 0], c1 = cwv[(size_t)b * 4 + 1], c2 = cwv[(size_t)b * 4 + 2];

    for (int dd = t; dd < ND; dd += 256) {
        const float rd = readv[(size_t)b * ND + dd];
        const float rh = read_h[(size_t)b * ND + dd];
        const float now = gk * rd, last = gm * rh;
        const float latest = (1.f - gk) * last + now;
        ctx_read[(size_t)b * ND + dd] = c0 * now + c1 * last + c2 * latest;
        float* hp = hist + (size_t)b * ND * NK + (size_t)dd * NK;
        float4 h0 = *(const float4*)&hp[0];
        float4 h1 = *(const float4*)&hp[4];
        h0.x = h0.x * (1.f - Wr[0]) + rd * Wr[0];
        h0.y = h0.y * (1.f - Wr[1]) + rd * Wr[1];
        h0.z = h0.z * (1.f - Wr[2]) + rd * Wr[2];
        h0.w = h0.w * (1.f - Wr[3]) + rd * Wr[3];
        h1.x = h1.x * (1.f - Wr[4]) + rd * Wr[4];
        h1.y = h1.y * (1.f - Wr[5]) + rd * Wr[5];
        h1.z = h1.z * (1.f - Wr[6]) + rd * Wr[6];
        h1.w = h1.w * (1.f - Wr[7]) + rd * Wr[7];
        *(float4*)&hp[0] = h0;
        *(float4*)&hp[4] = h1;
    }
    if (t == 0) {
        const float first = (1.f - gm) * gk;
        float nw[NK];
        #pragma unroll
        for (int k = 0; k < NK; ++k) nw[k] = wo[(k + 1) & 7] * first + wo[k] * (1.f - first);
        #pragma unroll
        for (int k = 0; k < NK; ++k) wts[(size_t)b * NK + k] = nw[k];
    }
}

// =====================================================================
extern "C" void kernel_launch(void* const* d_in, const int* in_sizes, int n_in,
                              void* d_out, int out_size, void* d_ws, size_t ws_size,
                              hipStream_t stream)
{
    (void)in_sizes; (void)n_in; (void)out_size; (void)ws_size;
    const float* context    = (const float*)d_in[0];
    const float* question   = (const float*)d_in[1];
    const float* knowledge  = (const float*)d_in[2];
    const float* kb_proj    = (const float*)d_in[3];
    const float* control0   = (const float*)d_in[4];
    const float* memory0    = (const float*)d_in[5];
    const float* history0   = (const float*)d_in[6];
    const float* wt0        = (const float*)d_in[7];
    const float* ctrl_pos_w = (const float*)d_in[8];
    const float* ctrl_pos_b = (const float*)d_in[9];
    const float* ctrl_cq_w  = (const float*)d_in[10];
    const float* ctrl_cq_b  = (const float*)d_in[11];
    const float* ctrl_attn_w= (const float*)d_in[12];
    // d_in[13] ctrl_attn_b: cancels in softmax
    const float* read_mem_w = (const float*)d_in[14];
    const float* read_mem_b = (const float*)d_in[15];
    const float* read_cat_w = (const float*)d_in[16];
    // d_in[17] read_cat_b: constant over h, cancels in softmax
    const float* read_attn_w= (const float*)d_in[18];
    // d_in[19] read_attn_b: cancels
    const float* rm_mem_w   = (const float*)d_in[20];
    const float* rm_mem_b   = (const float*)d_in[21];
    const float* rm_cat_w   = (const float*)d_in[22];
    // d_in[23] rm_cat_b: cancels
    const float* rm_attn_w  = (const float*)d_in[24];
    // d_in[25] rm_attn_b: cancels
    const float* write_w    = (const float*)d_in[26];
    const float* write_b    = (const float*)d_in[27];
    const float* lr_w1      = (const float*)d_in[28];
    const float* lr_b1      = (const float*)d_in[29];
    const float* lr_w2      = (const float*)d_in[30];
    const float* lr_b2      = (const float*)d_in[31];
    const float* lrh_w1     = (const float*)d_in[32];
    const float* lrh_b1     = (const float*)d_in[33];
    const float* lrh_w2     = (const float*)d_in[34];
    const float* lrh_b2     = (const float*)d_in[35];
    const float* mix_w1     = (const float*)d_in[36];
    const float* mix_b1     = (const float*)d_in[37];
    const float* mix_w2     = (const float*)d_in[38];
    const float* mix_b2     = (const float*)d_in[39];

    // ---- workspace layout (floats) ----
    float* w = (float*)d_ws;
    float* pa_all = w; w += (size_t)NB * 2048;   // (B, 4*512)
    float* cqi    = w; w += (size_t)NB * ND;
    float* control= w; w += (size_t)NB * ND;
    float* cw     = w; w += (size_t)NB * ND;
    float* cwh    = w; w += (size_t)NB * ND;
    float* mem_p  = w; w += (size_t)NB * ND;
    float* memh   = w; w += (size_t)NB * ND;
    float* u      = w; w += (size_t)NB * 2 * ND;
    float* uh     = w; w += (size_t)NB * 2 * ND;
    float* readv  = w; w += (size_t)NB * ND;
    float* read_h = w; w += (size_t)NB * ND;
    float* rvi    = w; w += (size_t)NB * NK;
    float* g1a    = w; w += (size_t)NB * 2 * ND;
    float* g1b    = w; w += (size_t)NB * 2 * ND;
    float* m1     = w; w += (size_t)NB * ND;
    float* gkb    = w; w += NB;
    float* gmem   = w; w += NB;
    float* cwv    = w; w += (size_t)NB * 4;
    float* ctx    = w; w += (size_t)NB * ND;
    float* hist   = w; w += (size_t)NB * ND * NK;
    float* wts    = w; w += (size_t)NB * NK;
    float* memA   = w; w += (size_t)NB * ND;
    float* memB   = w; w += (size_t)NB * ND;

    const dim3 blk(256);
    auto NT = [&](const float* A1, int lda1, int k1, const float* A2, int lda2,
                  const float* Bw, const float* bias, float* C, int N, int K, int act) {
        dim3 g(N / 64, NB / 32);
        if (act) gemm_k<true, 1><<<g, blk, 0, stream>>>(A1, lda1, k1, A2, lda2, Bw, bias, C, N, K);
        else     gemm_k<true, 0><<<g, blk, 0, stream>>>(A1, lda1, k1, A2, lda2, Bw, bias, C, N, K);
    };
    auto NN = [&](const float* A1, const float* Bw, float* C, int N, int K) {
        dim3 g(N / 64, NB / 32);
        gemm_k<false, 0><<<g, blk, 0, stream>>>(A1, K, K, A1, K, Bw, (const float*)nullptr, C, N, K);
    };

    // mutable state copies (must not modify d_in)
    hipMemcpyAsync(hist, history0, sizeof(float) * NB * ND * NK, hipMemcpyDeviceToDevice, stream);
    hipMemcpyAsync(wts,  wt0,      sizeof(float) * NB * NK,      hipMemcpyDeviceToDevice, stream);

    // pa for all 4 steps at once: (B,1024) @ (2048,1024)^T
    NT(question, 2 * ND, 2 * ND, question, 2 * ND, ctrl_pos_w, ctrl_pos_b, pa_all, 4 * ND, 2 * ND, 0);

    const float* ctrl_cur = control0;
    const float* mem_cur  = memory0;
    float* mem_bufs[2] = {memA, memB};

    for (int i = 0; i < NSTEP; ++i) {
        // cqi = [control, pa_i] @ ctrl_cq_w^T + b
        NT(ctrl_cur, ND, ND, pa_all + (size_t)i * ND, 4 * ND, ctrl_cq_w, ctrl_cq_b, cqi, ND, 2 * ND, 0);
        ctrl_attn_k<<<dim3(NB), blk, 0, stream>>>(cqi, context, ctrl_attn_w, read_attn_w, rm_attn_w,
                                                  control, cw, cwh);
        ctrl_cur = control;
        // mem projections
        NT(mem_cur, ND, ND, mem_cur, ND, read_mem_w, read_mem_b, mem_p, ND, ND, 0);
        NT(mem_cur, ND, ND, mem_cur, ND, rm_mem_w,   rm_mem_b,   memh,  ND, ND, 0);
        // u = cw @ read_cat_w  (d x 2d, row-major -> NN)
        NN(cw,  read_cat_w, u,  2 * ND, ND);
        NN(cwh, rm_cat_w,   uh, 2 * ND, ND);
        // attentions
        kb_attn_k  <<<dim3(NB), blk, 0, stream>>>(kb_proj, knowledge, mem_p, u, readv);
        hist_attn_k<<<dim3(NB), blk, 0, stream>>>(hist, memh, uh, rvi, read_h);
        // gate hidden layers (elu)
        NT(control, ND, ND, readv,  ND, lr_w1,  lr_b1,  g1a, 2 * ND, 2 * ND, 1);
        NT(control, ND, ND, read_h, ND, lrh_w1, lrh_b1, g1b, 2 * ND, 2 * ND, 1);
        NT(control, ND, ND, control, ND, mix_w1, mix_b1, m1, ND, ND, 1);
        scalars_k<<<dim3(NB), blk, 0, stream>>>(g1a, g1b, m1, lr_w2, lr_b2, lrh_w2, lrh_b2,
                                                mix_w2, mix_b2, gkb, gmem, cwv);
        update_k<<<dim3(NB), blk, 0, stream>>>(rvi, gkb, gmem, cwv, readv, read_h, hist, wts, ctx);
        // memory = [ctx_read, memory] @ write_w^T + b
        float* mem_out = (i == NSTEP - 1) ? (float*)d_out : mem_bufs[i & 1];
        NT(ctx, ND, ND, mem_cur, ND, write_w, write_b, mem_out, ND, 2 * ND, 0);
        mem_cur = mem_out;
    }
}

// Round 2
// 1282.537 us; speedup vs baseline: 2.1074x; 2.1074x over previous
//
#include <hip/hip_runtime.h>
#include <cstddef>

constexpr int NB   = 512;  // batch
constexpr int ND   = 512;  // dim
constexpr int NL   = 32;   // context length
constexpr int NHW  = 196;  // knowledge spatial
constexpr int NK   = 8;    // history slots
constexpr int NSTEP = 4;

typedef __attribute__((ext_vector_type(8))) short short8v;
typedef __attribute__((ext_vector_type(4))) float f32x4;

// split x into bf16 hi + bf16 lo (residual), both round-to-nearest-even
__device__ __forceinline__ void splitbf(float x, short& h, short& l) {
    unsigned u  = __float_as_uint(x);
    unsigned hb = (u + 0x7FFFu + ((u >> 16) & 1u)) & 0xFFFF0000u;
    h = (short)(hb >> 16);
    float rem = x - __uint_as_float(hb);
    unsigned v = __float_as_uint(rem);
    l = (short)((v + 0x7FFFu + ((v >> 16) & 1u)) >> 16);
}

// =====================================================================
// Split-bf16 MFMA GEMM (fp32-accurate): C = act(concat(A1,A2) @ Bw^T + bias)
//  A: fp32, rows M (per-problem 512), concat along K at k1 (k1 % 32 == 0)
//  B: pre-converted bf16 hi/lo, (N,K) row-major
//  Block: 256 thr (4 waves, 2x2), tile 64x64, BK=32. N%64==0, K%32==0.
//  Two problems (dual-M) selected by blockIdx.y half.
// =====================================================================
struct GemmP {
    const float* A1; const float* A2;
    int lda1, lda2, k1;
    const short* Bh; const short* Bl;
    const float* bias;
    float* C;
};

template<int ACT>   // 0 none, 1 elu
__global__ __launch_bounds__(256) void mgemm_k(GemmP p0, GemmP p1, int mtiles, int N, int K)
{
    __shared__ short Ah[64][32], Al[64][32], Bh[64][32], Bl[64][32];
    int my = blockIdx.y;
    const GemmP& p = (my < mtiles) ? p0 : p1;
    if (my >= mtiles) my -= mtiles;
    const int m0 = my * 64, n0 = blockIdx.x * 64;
    const int t = threadIdx.x, lane = t & 63, wid = t >> 6;
    const int wr = wid >> 1, wc = wid & 1;
    const int lr = lane & 15, lk = (lane >> 4) * 8;
    const int sr = t >> 2, skq = (t & 3) * 8;   // staging: row, k-offset

    f32x4 acc[2][2] = {};

    for (int kt = 0; kt < K; kt += 32) {
        // ---- stage A (fp32 -> bf16 hi/lo) ----
        {
            const int gm = m0 + sr, gk = kt + skq;
            const float* src = (gk < p.k1) ? p.A1 + (size_t)gm * p.lda1 + gk
                                           : p.A2 + (size_t)gm * p.lda2 + (gk - p.k1);
            float4 x0 = ((const float4*)src)[0];
            float4 x1 = ((const float4*)src)[1];
            float xs[8] = {x0.x, x0.y, x0.z, x0.w, x1.x, x1.y, x1.z, x1.w};
            short8v vh, vl;
            #pragma unroll
            for (int i = 0; i < 8; ++i) { short hh, ll; splitbf(xs[i], hh, ll); vh[i] = hh; vl[i] = ll; }
            *(short8v*)&Ah[sr][skq] = vh;
            *(short8v*)&Al[sr][skq] = vl;
        }
        // ---- stage B (bf16 direct) ----
        {
            const size_t off = (size_t)(n0 + sr) * K + kt + skq;
            *(short8v*)&Bh[sr][skq] = *(const short8v*)(p.Bh + off);
            *(short8v*)&Bl[sr][skq] = *(const short8v*)(p.Bl + off);
        }
        __syncthreads();
        short8v ah0 = *(short8v*)&Ah[wr * 32      + lr][lk];
        short8v ah1 = *(short8v*)&Ah[wr * 32 + 16 + lr][lk];
        short8v al0 = *(short8v*)&Al[wr * 32      + lr][lk];
        short8v al1 = *(short8v*)&Al[wr * 32 + 16 + lr][lk];
        short8v bh0 = *(short8v*)&Bh[wc * 32      + lr][lk];
        short8v bh1 = *(short8v*)&Bh[wc * 32 + 16 + lr][lk];
        short8v bl0 = *(short8v*)&Bl[wc * 32      + lr][lk];
        short8v bl1 = *(short8v*)&Bl[wc * 32 + 16 + lr][lk];

        acc[0][0] = __builtin_amdgcn_mfma_f32_16x16x32_bf16(ah0, bh0, acc[0][0], 0, 0, 0);
        acc[0][1] = __builtin_amdgcn_mfma_f32_16x16x32_bf16(ah0, bh1, acc[0][1], 0, 0, 0);
        acc[1][0] = __builtin_amdgcn_mfma_f32_16x16x32_bf16(ah1, bh0, acc[1][0], 0, 0, 0);
        acc[1][1] = __builtin_amdgcn_mfma_f32_16x16x32_bf16(ah1, bh1, acc[1][1], 0, 0, 0);
        acc[0][0] = __builtin_amdgcn_mfma_f32_16x16x32_bf16(al0, bh0, acc[0][0], 0, 0, 0);
        acc[0][1] = __builtin_amdgcn_mfma_f32_16x16x32_bf16(al0, bh1, acc[0][1], 0, 0, 0);
        acc[1][0] = __builtin_amdgcn_mfma_f32_16x16x32_bf16(al1, bh0, acc[1][0], 0, 0, 0);
        acc[1][1] = __builtin_amdgcn_mfma_f32_16x16x32_bf16(al1, bh1, acc[1][1], 0, 0, 0);
        acc[0][0] = __builtin_amdgcn_mfma_f32_16x16x32_bf16(ah0, bl0, acc[0][0], 0, 0, 0);
        acc[0][1] = __builtin_amdgcn_mfma_f32_16x16x32_bf16(ah0, bl1, acc[0][1], 0, 0, 0);
        acc[1][0] = __builtin_amdgcn_mfma_f32_16x16x32_bf16(ah1, bl0, acc[1][0], 0, 0, 0);
        acc[1][1] = __builtin_amdgcn_mfma_f32_16x16x32_bf16(ah1, bl1, acc[1][1], 0, 0, 0);
        __syncthreads();
    }
    #pragma unroll
    for (int fr = 0; fr < 2; ++fr)
    #pragma unroll
    for (int fc = 0; fc < 2; ++fc)
    #pragma unroll
    for (int rr = 0; rr < 4; ++rr) {
        const int row = m0 + wr * 32 + fr * 16 + (lane >> 4) * 4 + rr;
        const int col = n0 + wc * 32 + fc * 16 + lr;
        float x = acc[fr][fc][rr];
        if (p.bias) x += p.bias[col];
        if (ACT == 1) x = (x > 0.f) ? x : (expf(x) - 1.f);
        p.C[(size_t)row * N + col] = x;
    }
}

// =====================================================================
// Weight conversion prologue: fp32 -> bf16 hi/lo, up to 8 segments
// =====================================================================
struct WSeg { const float* src; short* dh; short* dl; int n; };
struct WTab { WSeg s[8]; int total; };

__global__ __launch_bounds__(256) void wconv_k(WTab tab)
{
    int i = blockIdx.x * 256 + threadIdx.x;
    if (i >= tab.total) return;
    int seg = 0, off = i;
    while (off >= tab.s[seg].n) { off -= tab.s[seg].n; ++seg; }
    short h, l; splitbf(tab.s[seg].src[off], h, l);
    tab.s[seg].dh[off] = h;
    tab.s[seg].dl[off] = l;
}

// Transpose-convert: src (512,1024) fp32 -> dst (1024,512) bf16 hi/lo
__global__ __launch_bounds__(256) void tconv_k(
    const float* s0, short* dh0, short* dl0,
    const float* s1, short* dh1, short* dl1)
{
    const float* src = blockIdx.z ? s1 : s0;
    short* dh = blockIdx.z ? dh1 : dh0;
    short* dl = blockIdx.z ? dl1 : dl0;
    __shared__ float tile[32][33];
    const int n0 = blockIdx.x * 32, k0 = blockIdx.y * 32;
    const int tx = threadIdx.x & 31, ty = threadIdx.x >> 5;
    for (int i = ty; i < 32; i += 8)
        tile[i][tx] = src[(size_t)(k0 + i) * 1024 + n0 + tx];
    __syncthreads();
    for (int i = ty; i < 32; i += 8) {
        short h, l; splitbf(tile[tx][i], h, l);
        dh[(size_t)(n0 + i) * 512 + k0 + tx] = h;
        dl[(size_t)(n0 + i) * 512 + k0 + tx] = l;
    }
}

// =====================================================================
// Control attention: 512 threads (8 waves), one block per batch element
// =====================================================================
__global__ __launch_bounds__(512) void ctrl_attn_k(
    const float* __restrict__ cqi, const float* __restrict__ context,
    const float* __restrict__ attn_w, const float* __restrict__ read_attn_w,
    const float* __restrict__ rm_attn_w,
    float* __restrict__ control, float* __restrict__ cw, float* __restrict__ cwh)
{
    const int b = blockIdx.x, t = threadIdx.x;
    const int lane = t & 63, w = t >> 6;
    __shared__ float q[ND];
    __shared__ float p[NL];
    const float* ctx = context + (size_t)b * NL * ND;

    q[t] = cqi[(size_t)b * ND + t] * attn_w[t];
    __syncthreads();

    for (int l = w; l < NL; l += 8) {
        float s = 0.f;
        const float* row = ctx + (size_t)l * ND;
        #pragma unroll
        for (int d = lane; d < ND; d += 64) s += q[d] * row[d];
        #pragma unroll
        for (int o = 32; o; o >>= 1) s += __shfl_down(s, o);
        if (lane == 0) p[l] = s;
    }
    __syncthreads();
    if (t == 0) {
        float mx = p[0];
        for (int l = 1; l < NL; ++l) mx = fmaxf(mx, p[l]);
        float sum = 0.f;
        for (int l = 0; l < NL; ++l) { float e = expf(p[l] - mx); p[l] = e; sum += e; }
        const float inv = 1.f / sum;
        for (int l = 0; l < NL; ++l) p[l] *= inv;
    }
    __syncthreads();
    float a = 0.f;
    #pragma unroll 8
    for (int l = 0; l < NL; ++l) a += p[l] * ctx[(size_t)l * ND + t];
    control[(size_t)b * ND + t] = a;
    cw [(size_t)b * ND + t] = a * read_attn_w[t];
    cwh[(size_t)b * ND + t] = a * rm_attn_w[t];
}

// =====================================================================
// KB score (partial): grid (4 j-chunks, B). s_part[(jc*B+b)*200 + h]
// =====================================================================
__global__ __launch_bounds__(256) void kb_score_k(
    const float* __restrict__ kb_proj, const float* __restrict__ mpc,
    const float* __restrict__ u, float* __restrict__ s_part)
{
    const int jc = blockIdx.x, b = blockIdx.y, t = threadIdx.x;
    __shared__ float v[128];
    const int j0 = jc * 128;
    if (t < 128) {
        const int j = j0 + t;
        v[t] = mpc[(size_t)b * 1024 + j] * u[(size_t)b * 1024 + j]
             + u[(size_t)b * 1024 + 512 + j];
    }
    __syncthreads();
    if (t < NHW) {
        const float* base = kb_proj + (size_t)b * ND * NHW + (size_t)j0 * NHW + t;
        float s = 0.f;
        #pragma unroll 8
        for (int j = 0; j < 128; ++j) s += base[(size_t)j * NHW] * v[j];
        s_part[((size_t)jc * NB + b) * 200 + t] = s;
    }
}

// =====================================================================
// KB read: grid (8 d-chunks, B). In-block softmax from partials (redundant,
// cheap), then read[d] = sum_h p[h]*knowledge[b,d,h]
// =====================================================================
__global__ __launch_bounds__(256) void kb_read_k(
    const float* __restrict__ knowledge, const float* __restrict__ s_part,
    float* __restrict__ readv)
{
    const int dcb = blockIdx.x, b = blockIdx.y, t = threadIdx.x;
    const int lane = t & 63, w = t >> 6;
    __shared__ float ps[200];
    __shared__ float red[8];

    float val = -INFINITY;
    if (t < NHW) {
        float sp = 0.f;
        #pragma unroll
        for (int jc = 0; jc < 4; ++jc) sp += s_part[((size_t)jc * NB + b) * 200 + t];
        val = sp;
    }
    float mx = val;
    #pragma unroll
    for (int o = 32; o; o >>= 1) mx = fmaxf(mx, __shfl_xor(mx, o));
    if (lane == 0) red[w] = mx;
    __syncthreads();
    mx = fmaxf(fmaxf(red[0], red[1]), fmaxf(red[2], red[3]));
    const float e = (t < NHW) ? expf(val - mx) : 0.f;
    float sm = e;
    #pragma unroll
    for (int o = 32; o; o >>= 1) sm += __shfl_xor(sm, o);
    if (lane == 0) red[4 + w] = sm;
    __syncthreads();
    const float tot = red[4] + red[5] + red[6] + red[7];
    if (t < 200) ps[t] = (t < NHW) ? e / tot : 0.f;
    __syncthreads();

    const float* knw = knowledge + (size_t)b * ND * NHW;
    const int d1 = dcb * 64 + 64;
    for (int d = dcb * 64 + w; d < d1; d += 4) {
        const float* row = knw + (size_t)d * NHW;
        float a = 0.f;
        for (int h = lane; h < NHW; h += 64) a += ps[h] * row[h];
        #pragma unroll
        for (int o = 32; o; o >>= 1) a += __shfl_down(a, o);
        if (lane == 0) readv[(size_t)b * ND + d] = a;
    }
}

// =====================================================================
// History attention (K=8 slots), one block per batch element
// =====================================================================
__global__ __launch_bounds__(256) void hist_attn_k(
    const float* __restrict__ hist, const float* __restrict__ mpc,
    const float* __restrict__ uh,
    float* __restrict__ rvi, float* __restrict__ read_h)
{
    const int b = blockIdx.x, t = threadIdx.x;
    const int lane = t & 63, w = t >> 6;
    __shared__ float ht[NK][ND];
    __shared__ float vh[ND];
    __shared__ float sred[NK];
    __shared__ float pk[NK];
    const float* hb = hist + (size_t)b * ND * NK;

    for (int dd = t; dd < ND; dd += 256) {
        float4 h0 = *(const float4*)&hb[(size_t)dd * NK];
        float4 h1 = *(const float4*)&hb[(size_t)dd * NK + 4];
        ht[0][dd] = h0.x; ht[1][dd] = h0.y; ht[2][dd] = h0.z; ht[3][dd] = h0.w;
        ht[4][dd] = h1.x; ht[5][dd] = h1.y; ht[6][dd] = h1.z; ht[7][dd] = h1.w;
        vh[dd] = mpc[(size_t)b * 1024 + 512 + dd] * uh[(size_t)b * 1024 + dd]
               + uh[(size_t)b * 1024 + 512 + dd];
    }
    __syncthreads();

    for (int k = w; k < NK; k += 4) {
        float s = 0.f;
        #pragma unroll 4
        for (int dd = lane; dd < ND; dd += 64) s += ht[k][dd] * vh[dd];
        #pragma unroll
        for (int o = 32; o; o >>= 1) s += __shfl_down(s, o);
        if (lane == 0) sred[k] = s;
    }
    __syncthreads();
    if (t == 0) {
        float mx = sred[0];
        #pragma unroll
        for (int k = 1; k < NK; ++k) mx = fmaxf(mx, sred[k]);
        float ev[NK]; float sum = 0.f;
        #pragma unroll
        for (int k = 0; k < NK; ++k) { ev[k] = expf(sred[k] - mx); sum += ev[k]; }
        const float inv = 1.f / sum;
        #pragma unroll
        for (int k = 0; k < NK; ++k) { float pv = ev[k] * inv; pk[k] = pv; rvi[(size_t)b * NK + k] = pv; }
    }
    __syncthreads();
    for (int dd = t; dd < ND; dd += 256) {
        float a = 0.f;
        #pragma unroll
        for (int k = 0; k < NK; ++k) a += pk[k] * ht[k][dd];
        read_h[(size_t)b * ND + dd] = a;
    }
}

// =====================================================================
// Merged scalars + state update, one block per batch element
// =====================================================================
__global__ __launch_bounds__(256) void update2_k(
    const float* __restrict__ g1a, const float* __restrict__ g1b,
    const float* __restrict__ m1,
    const float* __restrict__ lr_w2,  const float* __restrict__ lr_b2,
    const float* __restrict__ lrh_w2, const float* __restrict__ lrh_b2,
    const float* __restrict__ mix_w2, const float* __restrict__ mix_b2,
    const float* __restrict__ rvi, const float* __restrict__ readv,
    const float* __restrict__ read_h,
    float* __restrict__ hist, float* __restrict__ wts, float* __restrict__ ctx_read)
{
    const int b = blockIdx.x, t = threadIdx.x;
    const int lane = t & 63, w = t >> 6;
    __shared__ float red[4][5];
    __shared__ float sc[5];   // gk, gm, c0, c1, c2

    // ---- scalars phase ----
    float pa = 0.f, pb = 0.f, p0 = 0.f, p1 = 0.f, p2 = 0.f;
    for (int k = t; k < 2 * ND; k += 256) {
        pa += g1a[(size_t)b * 2 * ND + k] * lr_w2[k];
        pb += g1b[(size_t)b * 2 * ND + k] * lrh_w2[k];
    }
    for (int d = t; d < ND; d += 256) {
        const float m = m1[(size_t)b * ND + d];
        p0 += m * mix_w2[d];
        p1 += m * mix_w2[ND + d];
        p2 += m * mix_w2[2 * ND + d];
    }
    #pragma unroll
    for (int o = 32; o; o >>= 1) {
        pa += __shfl_down(pa, o); pb += __shfl_down(pb, o);
        p0 += __shfl_down(p0, o); p1 += __shfl_down(p1, o); p2 += __shfl_down(p2, o);
    }
    if (lane == 0) { red[w][0] = pa; red[w][1] = pb; red[w][2] = p0; red[w][3] = p1; red[w][4] = p2; }
    __syncthreads();
    if (t == 0) {
        float sa = 0.f, sb = 0.f, s0 = 0.f, s1 = 0.f, s2 = 0.f;
        #pragma unroll
        for (int i = 0; i < 4; ++i) { sa += red[i][0]; sb += red[i][1]; s0 += red[i][2]; s1 += red[i][3]; s2 += red[i][4]; }
        sc[0] = 1.f / (1.f + expf(-(sa + lr_b2[0])));
        sc[1] = 1.f / (1.f + expf(-(sb + lrh_b2[0])));
        const float l0 = s0 + mix_b2[0], l1 = s1 + mix_b2[1], l2 = s2 + mix_b2[2];
        const float mx = fmaxf(l0, fmaxf(l1, l2));
        const float e0 = expf(l0 - mx), e1 = expf(l1 - mx), e2 = expf(l2 - mx);
        const float inv = 1.f / (e0 + e1 + e2);
        sc[2] = e0 * inv; sc[3] = e1 * inv; sc[4] = e2 * inv;
    }
    __syncthreads();

    // ---- update phase ----
    const float gk = sc[0], gm = sc[1];
    const float c0 = sc[2], c1 = sc[3], c2 = sc[4];
    __shared__ float wo[NK], Ws[NK];
    if (t < NK) {
        const float w_old = wts[(size_t)b * NK + t];
        wo[t] = w_old;
        Ws[t] = (gm * rvi[(size_t)b * NK + t] + w_old * (1.f - gm)) * gk;
    }
    __syncthreads();
    float Wr[NK];
    #pragma unroll
    for (int k = 0; k < NK; ++k) Wr[k] = Ws[k];

    for (int dd = t; dd < ND; dd += 256) {
        const float rd = readv[(size_t)b * ND + dd];
        const float rh = read_h[(size_t)b * ND + dd];
        const float now = gk * rd, last = gm * rh;
        const float latest = (1.f - gk) * last + now;
        ctx_read[(size_t)b * ND + dd] = c0 * now + c1 * last + c2 * latest;
        float* hp = hist + (size_t)b * ND * NK + (size_t)dd * NK;
        float4 h0 = *(const float4*)&hp[0];
        float4 h1 = *(const float4*)&hp[4];
        h0.x = h0.x * (1.f - Wr[0]) + rd * Wr[0];
        h0.y = h0.y * (1.f - Wr[1]) + rd * Wr[1];
        h0.z = h0.z * (1.f - Wr[2]) + rd * Wr[2];
        h0.w = h0.w * (1.f - Wr[3]) + rd * Wr[3];
        h1.x = h1.x * (1.f - Wr[4]) + rd * Wr[4];
        h1.y = h1.y * (1.f - Wr[5]) + rd * Wr[5];
        h1.z = h1.z * (1.f - Wr[6]) + rd * Wr[6];
        h1.w = h1.w * (1.f - Wr[7]) + rd * Wr[7];
        *(float4*)&hp[0] = h0;
        *(float4*)&hp[4] = h1;
    }
    if (t == 0) {
        const float first = (1.f - gm) * gk;
        float nw[NK];
        #pragma unroll
        for (int k = 0; k < NK; ++k) nw[k] = wo[(k + 1) & 7] * first + wo[k] * (1.f - first);
        #pragma unroll
        for (int k = 0; k < NK; ++k) wts[(size_t)b * NK + k] = nw[k];
    }
}

// =====================================================================
extern "C" void kernel_launch(void* const* d_in, const int* in_sizes, int n_in,
                              void* d_out, int out_size, void* d_ws, size_t ws_size,
                              hipStream_t stream)
{
    (void)in_sizes; (void)n_in; (void)out_size; (void)ws_size;
    const float* context    = (const float*)d_in[0];
    const float* question   = (const float*)d_in[1];
    const float* knowledge  = (const float*)d_in[2];
    const float* kb_proj    = (const float*)d_in[3];
    const float* control0   = (const float*)d_in[4];
    const float* memory0    = (const float*)d_in[5];
    const float* history0   = (const float*)d_in[6];
    const float* wt0        = (const float*)d_in[7];
    const float* ctrl_pos_w = (const float*)d_in[8];
    const float* ctrl_pos_b = (const float*)d_in[9];
    const float* ctrl_cq_w  = (const float*)d_in[10];
    const float* ctrl_cq_b  = (const float*)d_in[11];
    const float* ctrl_attn_w= (const float*)d_in[12];
    const float* read_mem_w = (const float*)d_in[14];
    const float* read_mem_b = (const float*)d_in[15];
    const float* read_cat_w = (const float*)d_in[16];
    const float* read_attn_w= (const float*)d_in[18];
    const float* rm_mem_w   = (const float*)d_in[20];
    const float* rm_mem_b   = (const float*)d_in[21];
    const float* rm_cat_w   = (const float*)d_in[22];
    const float* rm_attn_w  = (const float*)d_in[24];
    const float* write_w    = (const float*)d_in[26];
    const float* write_b    = (const float*)d_in[27];
    const float* lr_w1      = (const float*)d_in[28];
    const float* lr_b1      = (const float*)d_in[29];
    const float* lr_w2      = (const float*)d_in[30];
    const float* lr_b2      = (const float*)d_in[31];
    const float* lrh_w1     = (const float*)d_in[32];
    const float* lrh_b1     = (const float*)d_in[33];
    const float* lrh_w2     = (const float*)d_in[34];
    const float* lrh_b2     = (const float*)d_in[35];
    const float* mix_w1     = (const float*)d_in[36];
    const float* mix_b1     = (const float*)d_in[37];
    const float* mix_w2     = (const float*)d_in[38];
    const float* mix_b2     = (const float*)d_in[39];

    // ---- workspace: floats then bf16 hi/lo shorts ----
    float* f = (float*)d_ws;
    auto takef = [&](size_t n) { float* p = f; f += n; return p; };
    float* pa_all = takef((size_t)NB * 2048);
    float* cqi    = takef((size_t)NB * ND);
    float* control= takef((size_t)NB * ND);
    float* cw     = takef((size_t)NB * ND);
    float* cwh    = takef((size_t)NB * ND);
    float* mpc    = takef((size_t)NB * 1024);   // [mem_p | memh]
    float* u      = takef((size_t)NB * 1024);
    float* uh     = takef((size_t)NB * 1024);
    float* readv  = takef((size_t)NB * ND);
    float* read_h = takef((size_t)NB * ND);
    float* rvi    = takef((size_t)NB * NK);
    float* g1a    = takef((size_t)NB * 1024);
    float* g1b    = takef((size_t)NB * 1024);
    float* m1buf  = takef((size_t)NB * ND);
    float* ctx    = takef((size_t)NB * ND);
    float* hist   = takef((size_t)NB * ND * NK);
    float* wts    = takef((size_t)NB * NK);
    float* memA   = takef((size_t)NB * ND);
    float* memB   = takef((size_t)NB * ND);
    float* s_part = takef((size_t)4 * NB * 200);
    float* bcat   = takef(1024);

    short* s = (short*)f;
    auto takes = [&](size_t n) { short* p = s; s += n; return p; };
    short* cpw_h = takes((size_t)2048 * 1024); short* cpw_l = takes((size_t)2048 * 1024);
    short* cqw_h = takes((size_t)512 * 1024);  short* cqw_l = takes((size_t)512 * 1024);
    short* wmc_h = takes((size_t)1024 * 512);  short* wmc_l = takes((size_t)1024 * 512);
    short* rcw_h = takes((size_t)1024 * 512);  short* rcw_l = takes((size_t)1024 * 512);
    short* rmw_h = takes((size_t)1024 * 512);  short* rmw_l = takes((size_t)1024 * 512);
    short* lrw_h = takes((size_t)1024 * 1024); short* lrw_l = takes((size_t)1024 * 1024);
    short* lhw_h = takes((size_t)1024 * 1024); short* lhw_l = takes((size_t)1024 * 1024);
    short* mxw_h = takes((size_t)512 * 512);   short* mxw_l = takes((size_t)512 * 512);
    short* ww_h  = takes((size_t)512 * 1024);  short* ww_l  = takes((size_t)512 * 1024);

    // ---- prologue: state copies + weight conversion ----
    hipMemcpyAsync(hist, history0, sizeof(float) * NB * ND * NK, hipMemcpyDeviceToDevice, stream);
    hipMemcpyAsync(wts,  wt0,      sizeof(float) * NB * NK,      hipMemcpyDeviceToDevice, stream);
    hipMemcpyAsync(bcat,       read_mem_b, sizeof(float) * 512, hipMemcpyDeviceToDevice, stream);
    hipMemcpyAsync(bcat + 512, rm_mem_b,   sizeof(float) * 512, hipMemcpyDeviceToDevice, stream);

    WTab tab;
    tab.s[0] = {ctrl_pos_w, cpw_h, cpw_l, 2048 * 1024};
    tab.s[1] = {ctrl_cq_w,  cqw_h, cqw_l, 512 * 1024};
    tab.s[2] = {read_mem_w, wmc_h, wmc_l, 512 * 512};
    tab.s[3] = {rm_mem_w,   wmc_h + 512 * 512, wmc_l + 512 * 512, 512 * 512};
    tab.s[4] = {lr_w1,  lrw_h, lrw_l, 1024 * 1024};
    tab.s[5] = {lrh_w1, lhw_h, lhw_l, 1024 * 1024};
    tab.s[6] = {mix_w1, mxw_h, mxw_l, 512 * 512};
    tab.s[7] = {write_w, ww_h, ww_l, 512 * 1024};
    tab.total = 2048*1024 + 512*1024 + 512*512 + 512*512 + 1024*1024 + 1024*1024 + 512*512 + 512*1024;
    wconv_k<<<dim3((tab.total + 255) / 256), dim3(256), 0, stream>>>(tab);
    tconv_k<<<dim3(32, 16, 2), dim3(256), 0, stream>>>(read_cat_w, rcw_h, rcw_l,
                                                       rm_cat_w,  rmw_h, rmw_l);

    auto MG1 = [&](GemmP p, int N, int K, int act) {
        dim3 g(N / 64, 8);
        if (act) mgemm_k<1><<<g, dim3(256), 0, stream>>>(p, p, 8, N, K);
        else     mgemm_k<0><<<g, dim3(256), 0, stream>>>(p, p, 8, N, K);
    };
    auto MG2 = [&](GemmP p0, GemmP p1, int N, int K, int act) {
        dim3 g(N / 64, 16);
        if (act) mgemm_k<1><<<g, dim3(256), 0, stream>>>(p0, p1, 8, N, K);
        else     mgemm_k<0><<<g, dim3(256), 0, stream>>>(p0, p1, 8, N, K);
    };

    // pa for all 4 steps: (B,1024) @ ctrl_pos_w(2048,1024)^T
    MG1({question, question, 1024, 1024, 1024, cpw_h, cpw_l, ctrl_pos_b, pa_all}, 2048, 1024, 0);

    const float* ctrl_cur = control0;
    const float* mem_cur  = memory0;
    float* mem_bufs[2] = {memA, memB};

    for (int i = 0; i < NSTEP; ++i) {
        MG1({ctrl_cur, pa_all + (size_t)i * ND, ND, 2048, ND, cqw_h, cqw_l, ctrl_cq_b, cqi},
            ND, 1024, 0);
        ctrl_attn_k<<<dim3(NB), dim3(512), 0, stream>>>(cqi, context, ctrl_attn_w,
                                                        read_attn_w, rm_attn_w, control, cw, cwh);
        ctrl_cur = control;
        MG1({mem_cur, mem_cur, ND, ND, ND, wmc_h, wmc_l, bcat, mpc}, 1024, ND, 0);
        MG2({cw,  cw,  ND, ND, ND, rcw_h, rcw_l, nullptr, u},
            {cwh, cwh, ND, ND, ND, rmw_h, rmw_l, nullptr, uh}, 1024, ND, 0);
        kb_score_k<<<dim3(4, NB), dim3(256), 0, stream>>>(kb_proj, mpc, u, s_part);
        hist_attn_k<<<dim3(NB), dim3(256), 0, stream>>>(hist, mpc, uh, rvi, read_h);
        kb_read_k<<<dim3(8, NB), dim3(256), 0, stream>>>(knowledge, s_part, readv);
        MG2({control, readv,  ND, ND, ND, lrw_h, lrw_l, lr_b1,  g1a},
            {control, read_h, ND, ND, ND, lhw_h, lhw_l, lrh_b1, g1b}, 1024, 1024, 1);
        MG1({control, control, ND, ND, ND, mxw_h, mxw_l, mix_b1, m1buf}, ND, ND, 1);
        update2_k<<<dim3(NB), dim3(256), 0, stream>>>(g1a, g1b, m1buf,
                                                      lr_w2, lr_b2, lrh_w2, lrh_b2,
                                                      mix_w2, mix_b2, rvi, readv, read_h,
                                                      hist, wts, ctx);
        float* mem_out = (i == NSTEP - 1) ? (float*)d_out : mem_bufs[i & 1];
        MG1({ctx, mem_cur, ND, ND, ND, ww_h, ww_l, write_b, mem_out}, ND, 1024, 0);
        mem_cur = mem_out;
    }
}

// Round 3
// 960.736 us; speedup vs baseline: 2.8133x; 1.3350x over previous
//
#include <hip/hip_runtime.h>
#include <cstddef>

constexpr int NB   = 512;  // batch
constexpr int ND   = 512;  // dim
constexpr int NL   = 32;   // context length
constexpr int NHW  = 196;  // knowledge spatial
constexpr int NK   = 8;    // history slots
constexpr int NSTEP = 4;

typedef __attribute__((ext_vector_type(8))) short short8v;
typedef __attribute__((ext_vector_type(4))) short short4v;
typedef __attribute__((ext_vector_type(4))) float f32x4;

// split x into bf16 hi + bf16 lo (residual), both round-to-nearest-even
__device__ __forceinline__ void splitbf(float x, short& h, short& l) {
    unsigned u  = __float_as_uint(x);
    unsigned hb = (u + 0x7FFFu + ((u >> 16) & 1u)) & 0xFFFF0000u;
    h = (short)(hb >> 16);
    float rem = x - __uint_as_float(hb);
    unsigned v = __float_as_uint(rem);
    l = (short)((v + 0x7FFFu + ((v >> 16) & 1u)) >> 16);
}

// =====================================================================
// Grouped split-bf16 MFMA GEMM: up to 3 problems per launch.
//  Each problem: C = act(concat(A1,A2) @ Bw^T + bias), M = 512 rows.
//  Tile 32(M) x 64(N) x 32(K), 256 thr (4 waves as 2Mx2N of 16x32).
//  B pre-converted bf16 hi/lo, (N,K) row-major. k1 % 32 == 0, K % 32 == 0.
// =====================================================================
struct GP {
    const float* A1; const float* A2;
    const short* Bh; const short* Bl;
    const float* bias; float* C;
    int lda1, lda2, k1, N, K, ntN, tile0;
};
struct GP3 { GP p[3]; int np; };

template<int ACT>   // 0 none, 1 elu
__global__ __launch_bounds__(256) void ggemm_k(GP3 g)
{
    __shared__ short Ah[32][32], Al[32][32], Bh_s[64][32], Bl_s[64][32];
    const int flat = blockIdx.x;
    int pi = 0;
    if (g.np > 1 && flat >= g.p[1].tile0) pi = 1;
    if (g.np > 2 && flat >= g.p[2].tile0) pi = 2;
    const GP p = g.p[pi];
    const int local = flat - p.tile0;
    const int my = local / p.ntN;
    const int nx = local - my * p.ntN;
    const int m0 = my * 32, n0 = nx * 64;
    const int t = threadIdx.x, lane = t & 63, wid = t >> 6;
    const int wr = wid >> 1, wc = wid & 1;
    const int lr = lane & 15, lk = (lane >> 4) * 8;
    const int asr = t >> 3, asc = (t & 7) * 4;
    const int bsr = t >> 2, bsk = (t & 3) * 8;
    f32x4 acc0 = {}, acc1 = {};

    for (int kt = 0; kt < p.K; kt += 32) {
        // ---- stage A (fp32 -> bf16 hi/lo), 32x32 ----
        {
            const int gk = kt + asc;
            const float* src = (gk < p.k1) ? p.A1 + (size_t)(m0 + asr) * p.lda1 + gk
                                           : p.A2 + (size_t)(m0 + asr) * p.lda2 + (gk - p.k1);
            float4 x = *(const float4*)src;
            short4v vh, vl; short hh, ll;
            splitbf(x.x, hh, ll); vh[0] = hh; vl[0] = ll;
            splitbf(x.y, hh, ll); vh[1] = hh; vl[1] = ll;
            splitbf(x.z, hh, ll); vh[2] = hh; vl[2] = ll;
            splitbf(x.w, hh, ll); vh[3] = hh; vl[3] = ll;
            *(short4v*)&Ah[asr][asc] = vh;
            *(short4v*)&Al[asr][asc] = vl;
        }
        // ---- stage B (bf16 direct), 64x32 ----
        {
            const size_t boff = (size_t)(n0 + bsr) * p.K + kt + bsk;
            *(short8v*)&Bh_s[bsr][bsk] = *(const short8v*)(p.Bh + boff);
            *(short8v*)&Bl_s[bsr][bsk] = *(const short8v*)(p.Bl + boff);
        }
        __syncthreads();
        short8v ah  = *(short8v*)&Ah[wr * 16 + lr][lk];
        short8v al  = *(short8v*)&Al[wr * 16 + lr][lk];
        short8v bh0 = *(short8v*)&Bh_s[wc * 32      + lr][lk];
        short8v bh1 = *(short8v*)&Bh_s[wc * 32 + 16 + lr][lk];
        short8v bl0 = *(short8v*)&Bl_s[wc * 32      + lr][lk];
        short8v bl1 = *(short8v*)&Bl_s[wc * 32 + 16 + lr][lk];
        acc0 = __builtin_amdgcn_mfma_f32_16x16x32_bf16(ah, bh0, acc0, 0, 0, 0);
        acc1 = __builtin_amdgcn_mfma_f32_16x16x32_bf16(ah, bh1, acc1, 0, 0, 0);
        acc0 = __builtin_amdgcn_mfma_f32_16x16x32_bf16(al, bh0, acc0, 0, 0, 0);
        acc1 = __builtin_amdgcn_mfma_f32_16x16x32_bf16(al, bh1, acc1, 0, 0, 0);
        acc0 = __builtin_amdgcn_mfma_f32_16x16x32_bf16(ah, bl0, acc0, 0, 0, 0);
        acc1 = __builtin_amdgcn_mfma_f32_16x16x32_bf16(ah, bl1, acc1, 0, 0, 0);
        __syncthreads();
    }
    const int r0 = m0 + wr * 16 + (lane >> 4) * 4;
    const int cb = n0 + wc * 32 + lr;
    #pragma unroll
    for (int fc = 0; fc < 2; ++fc) {
        const f32x4& a = fc ? acc1 : acc0;
        const int col = cb + fc * 16;
        float badd = p.bias ? p.bias[col] : 0.f;
        #pragma unroll
        for (int rr = 0; rr < 4; ++rr) {
            float x = a[rr] + badd;
            if (ACT == 1) x = (x > 0.f) ? x : (expf(x) - 1.f);
            p.C[(size_t)(r0 + rr) * p.N + col] = x;
        }
    }
}

// =====================================================================
// Weight conversion prologue: fp32 -> bf16 hi/lo, up to 8 segments
// =====================================================================
struct WSeg { const float* src; short* dh; short* dl; int n; };
struct WTab { WSeg s[8]; int total; };

__global__ __launch_bounds__(256) void wconv_k(WTab tab)
{
    int i = blockIdx.x * 256 + threadIdx.x;
    if (i >= tab.total) return;
    int seg = 0, off = i;
    while (off >= tab.s[seg].n) { off -= tab.s[seg].n; ++seg; }
    short h, l; splitbf(tab.s[seg].src[off], h, l);
    tab.s[seg].dh[off] = h;
    tab.s[seg].dl[off] = l;
}

// Transpose-convert: src (512,1024) fp32 -> dst (1024,512) bf16 hi/lo
__global__ __launch_bounds__(256) void tconv_k(
    const float* s0, short* dh0, short* dl0,
    const float* s1, short* dh1, short* dl1)
{
    const float* src = blockIdx.z ? s1 : s0;
    short* dh = blockIdx.z ? dh1 : dh0;
    short* dl = blockIdx.z ? dl1 : dl0;
    __shared__ float tile[32][33];
    const int n0 = blockIdx.x * 32, k0 = blockIdx.y * 32;
    const int tx = threadIdx.x & 31, ty = threadIdx.x >> 5;
    for (int i = ty; i < 32; i += 8)
        tile[i][tx] = src[(size_t)(k0 + i) * 1024 + n0 + tx];
    __syncthreads();
    for (int i = ty; i < 32; i += 8) {
        short h, l; splitbf(tile[tx][i], h, l);
        dh[(size_t)(n0 + i) * 512 + k0 + tx] = h;
        dl[(size_t)(n0 + i) * 512 + k0 + tx] = l;
    }
}

// =====================================================================
// Control attention: 512 threads (8 waves), one block per batch element
// =====================================================================
__global__ __launch_bounds__(512) void ctrl_attn_k(
    const float* __restrict__ cqi, const float* __restrict__ context,
    const float* __restrict__ attn_w, const float* __restrict__ read_attn_w,
    const float* __restrict__ rm_attn_w,
    float* __restrict__ control, float* __restrict__ cw, float* __restrict__ cwh)
{
    const int b = blockIdx.x, t = threadIdx.x;
    const int lane = t & 63, w = t >> 6;
    __shared__ float q[ND];
    __shared__ float p[NL];
    const float* ctx = context + (size_t)b * NL * ND;

    q[t] = cqi[(size_t)b * ND + t] * attn_w[t];
    __syncthreads();

    for (int l = w; l < NL; l += 8) {
        float s = 0.f;
        const float* row = ctx + (size_t)l * ND;
        #pragma unroll
        for (int d = lane; d < ND; d += 64) s += q[d] * row[d];
        #pragma unroll
        for (int o = 32; o; o >>= 1) s += __shfl_down(s, o);
        if (lane == 0) p[l] = s;
    }
    __syncthreads();
    if (t == 0) {
        float mx = p[0];
        for (int l = 1; l < NL; ++l) mx = fmaxf(mx, p[l]);
        float sum = 0.f;
        for (int l = 0; l < NL; ++l) { float e = expf(p[l] - mx); p[l] = e; sum += e; }
        const float inv = 1.f / sum;
        for (int l = 0; l < NL; ++l) p[l] *= inv;
    }
    __syncthreads();
    float a = 0.f;
    #pragma unroll 8
    for (int l = 0; l < NL; ++l) a += p[l] * ctx[(size_t)l * ND + t];
    control[(size_t)b * ND + t] = a;
    cw [(size_t)b * ND + t] = a * read_attn_w[t];
    cwh[(size_t)b * ND + t] = a * rm_attn_w[t];
}

// =====================================================================
// Merged kb_score + hist_attn.
//  blocks [0, 4*NB): kb partial scores, jc = bx>>9, b = bx&511
//  blocks [4*NB, 5*NB): history attention, b = bx - 4*NB
// =====================================================================
__global__ __launch_bounds__(256) void kbsh_k(
    const float* __restrict__ kb_proj, const float* __restrict__ mpc,
    const float* __restrict__ u, float* __restrict__ s_part,
    const float* __restrict__ hist, const float* __restrict__ uh,
    float* __restrict__ rvi, float* __restrict__ read_h)
{
    __shared__ float sh[NK * ND + ND];   // 18 KB
    __shared__ float sred[NK], pk[NK];
    const int bx = blockIdx.x, t = threadIdx.x;
    const int lane = t & 63, w = t >> 6;

    if (bx < 4 * NB) {
        // ---------------- kb_score ----------------
        const int jc = bx >> 9, b = bx & 511;
        float* v = sh;
        const int j0 = jc * 128;
        if (t < 128) {
            const int j = j0 + t;
            v[t] = mpc[(size_t)b * 1024 + j] * u[(size_t)b * 1024 + j]
                 + u[(size_t)b * 1024 + 512 + j];
        }
        __syncthreads();
        if (t < NHW) {
            const float* base = kb_proj + (size_t)b * ND * NHW + (size_t)j0 * NHW + t;
            float s = 0.f;
            #pragma unroll 8
            for (int j = 0; j < 128; ++j) s += base[(size_t)j * NHW] * v[j];
            s_part[((size_t)jc * NB + b) * 200 + t] = s;
        }
    } else {
        // ---------------- hist_attn ----------------
        const int b = bx - 4 * NB;
        float* ht = sh;             // [NK][ND]
        float* vh = sh + NK * ND;   // [ND]
        const float* hb = hist + (size_t)b * ND * NK;

        for (int dd = t; dd < ND; dd += 256) {
            float4 h0 = *(const float4*)&hb[(size_t)dd * NK];
            float4 h1 = *(const float4*)&hb[(size_t)dd * NK + 4];
            ht[0 * ND + dd] = h0.x; ht[1 * ND + dd] = h0.y;
            ht[2 * ND + dd] = h0.z; ht[3 * ND + dd] = h0.w;
            ht[4 * ND + dd] = h1.x; ht[5 * ND + dd] = h1.y;
            ht[6 * ND + dd] = h1.z; ht[7 * ND + dd] = h1.w;
            vh[dd] = mpc[(size_t)b * 1024 + 512 + dd] * uh[(size_t)b * 1024 + dd]
                   + uh[(size_t)b * 1024 + 512 + dd];
        }
        __syncthreads();

        for (int k = w; k < NK; k += 4) {
            float s = 0.f;
            #pragma unroll 4
            for (int dd = lane; dd < ND; dd += 64) s += ht[k * ND + dd] * vh[dd];
            #pragma unroll
            for (int o = 32; o; o >>= 1) s += __shfl_down(s, o);
            if (lane == 0) sred[k] = s;
        }
        __syncthreads();
        if (t == 0) {
            float mx = sred[0];
            #pragma unroll
            for (int k = 1; k < NK; ++k) mx = fmaxf(mx, sred[k]);
            float ev[NK]; float sum = 0.f;
            #pragma unroll
            for (int k = 0; k < NK; ++k) { ev[k] = expf(sred[k] - mx); sum += ev[k]; }
            const float inv = 1.f / sum;
            #pragma unroll
            for (int k = 0; k < NK; ++k) { float pv = ev[k] * inv; pk[k] = pv; rvi[(size_t)b * NK + k] = pv; }
        }
        __syncthreads();
        for (int dd = t; dd < ND; dd += 256) {
            float a = 0.f;
            #pragma unroll
            for (int k = 0; k < NK; ++k) a += pk[k] * ht[k * ND + dd];
            read_h[(size_t)b * ND + dd] = a;
        }
    }
}

// =====================================================================
// KB read: grid (8 d-chunks, B). In-block softmax from partials, then
// read[d] = sum_h p[h]*knowledge[b,d,h]
// =====================================================================
__global__ __launch_bounds__(256) void kb_read_k(
    const float* __restrict__ knowledge, const float* __restrict__ s_part,
    float* __restrict__ readv)
{
    const int dcb = blockIdx.x, b = blockIdx.y, t = threadIdx.x;
    const int lane = t & 63, w = t >> 6;
    __shared__ float ps[200];
    __shared__ float red[8];

    float val = -INFINITY;
    if (t < NHW) {
        float sp = 0.f;
        #pragma unroll
        for (int jc = 0; jc < 4; ++jc) sp += s_part[((size_t)jc * NB + b) * 200 + t];
        val = sp;
    }
    float mx = val;
    #pragma unroll
    for (int o = 32; o; o >>= 1) mx = fmaxf(mx, __shfl_xor(mx, o));
    if (lane == 0) red[w] = mx;
    __syncthreads();
    mx = fmaxf(fmaxf(red[0], red[1]), fmaxf(red[2], red[3]));
    const float e = (t < NHW) ? expf(val - mx) : 0.f;
    float sm = e;
    #pragma unroll
    for (int o = 32; o; o >>= 1) sm += __shfl_xor(sm, o);
    if (lane == 0) red[4 + w] = sm;
    __syncthreads();
    const float tot = red[4] + red[5] + red[6] + red[7];
    if (t < 200) ps[t] = (t < NHW) ? e / tot : 0.f;
    __syncthreads();

    const float* knw = knowledge + (size_t)b * ND * NHW;
    const int d1 = dcb * 64 + 64;
    for (int d = dcb * 64 + w; d < d1; d += 4) {
        const float* row = knw + (size_t)d * NHW;
        float a = 0.f;
        for (int h = lane; h < NHW; h += 64) a += ps[h] * row[h];
        #pragma unroll
        for (int o = 32; o; o >>= 1) a += __shfl_down(a, o);
        if (lane == 0) readv[(size_t)b * ND + d] = a;
    }
}

// =====================================================================
// Merged scalars + state update, one block per batch element
// =====================================================================
__global__ __launch_bounds__(256) void update2_k(
    const float* __restrict__ g1a, const float* __restrict__ g1b,
    const float* __restrict__ m1,
    const float* __restrict__ lr_w2,  const float* __restrict__ lr_b2,
    const float* __restrict__ lrh_w2, const float* __restrict__ lrh_b2,
    const float* __restrict__ mix_w2, const float* __restrict__ mix_b2,
    const float* __restrict__ rvi, const float* __restrict__ readv,
    const float* __restrict__ read_h,
    float* __restrict__ hist, float* __restrict__ wts, float* __restrict__ ctx_read)
{
    const int b = blockIdx.x, t = threadIdx.x;
    const int lane = t & 63, w = t >> 6;
    __shared__ float red[4][5];
    __shared__ float sc[5];   // gk, gm, c0, c1, c2

    float pa = 0.f, pb = 0.f, p0 = 0.f, p1 = 0.f, p2 = 0.f;
    for (int k = t; k < 2 * ND; k += 256) {
        pa += g1a[(size_t)b * 2 * ND + k] * lr_w2[k];
        pb += g1b[(size_t)b * 2 * ND + k] * lrh_w2[k];
    }
    for (int d = t; d < ND; d += 256) {
        const float m = m1[(size_t)b * ND + d];
        p0 += m * mix_w2[d];
        p1 += m * mix_w2[ND + d];
        p2 += m * mix_w2[2 * ND + d];
    }
    #pragma unroll
    for (int o = 32; o; o >>= 1) {
        pa += __shfl_down(pa, o); pb += __shfl_down(pb, o);
        p0 += __shfl_down(p0, o); p1 += __shfl_down(p1, o); p2 += __shfl_down(p2, o);
    }
    if (lane == 0) { red[w][0] = pa; red[w][1] = pb; red[w][2] = p0; red[w][3] = p1; red[w][4] = p2; }
    __syncthreads();
    if (t == 0) {
        float sa = 0.f, sb = 0.f, s0 = 0.f, s1 = 0.f, s2 = 0.f;
        #pragma unroll
        for (int i = 0; i < 4; ++i) { sa += red[i][0]; sb += red[i][1]; s0 += red[i][2]; s1 += red[i][3]; s2 += red[i][4]; }
        sc[0] = 1.f / (1.f + expf(-(sa + lr_b2[0])));
        sc[1] = 1.f / (1.f + expf(-(sb + lrh_b2[0])));
        const float l0 = s0 + mix_b2[0], l1 = s1 + mix_b2[1], l2 = s2 + mix_b2[2];
        const float mx = fmaxf(l0, fmaxf(l1, l2));
        const float e0 = expf(l0 - mx), e1 = expf(l1 - mx), e2 = expf(l2 - mx);
        const float inv = 1.f / (e0 + e1 + e2);
        sc[2] = e0 * inv; sc[3] = e1 * inv; sc[4] = e2 * inv;
    }
    __syncthreads();

    const float gk = sc[0], gm = sc[1];
    const float c0 = sc[2], c1 = sc[3], c2 = sc[4];
    __shared__ float wo[NK], Ws[NK];
    if (t < NK) {
        const float w_old = wts[(size_t)b * NK + t];
        wo[t] = w_old;
        Ws[t] = (gm * rvi[(size_t)b * NK + t] + w_old * (1.f - gm)) * gk;
    }
    __syncthreads();
    float Wr[NK];
    #pragma unroll
    for (int k = 0; k < NK; ++k) Wr[k] = Ws[k];

    for (int dd = t; dd < ND; dd += 256) {
        const float rd = readv[(size_t)b * ND + dd];
        const float rh = read_h[(size_t)b * ND + dd];
        const float now = gk * rd, last = gm * rh;
        const float latest = (1.f - gk) * last + now;
        ctx_read[(size_t)b * ND + dd] = c0 * now + c1 * last + c2 * latest;
        float* hp = hist + (size_t)b * ND * NK + (size_t)dd * NK;
        float4 h0 = *(const float4*)&hp[0];
        float4 h1 = *(const float4*)&hp[4];
        h0.x = h0.x * (1.f - Wr[0]) + rd * Wr[0];
        h0.y = h0.y * (1.f - Wr[1]) + rd * Wr[1];
        h0.z = h0.z * (1.f - Wr[2]) + rd * Wr[2];
        h0.w = h0.w * (1.f - Wr[3]) + rd * Wr[3];
        h1.x = h1.x * (1.f - Wr[4]) + rd * Wr[4];
        h1.y = h1.y * (1.f - Wr[5]) + rd * Wr[5];
        h1.z = h1.z * (1.f - Wr[6]) + rd * Wr[6];
        h1.w = h1.w * (1.f - Wr[7]) + rd * Wr[7];
        *(float4*)&hp[0] = h0;
        *(float4*)&hp[4] = h1;
    }
    if (t == 0) {
        const float first = (1.f - gm) * gk;
        float nw[NK];
        #pragma unroll
        for (int k = 0; k < NK; ++k) nw[k] = wo[(k + 1) & 7] * first + wo[k] * (1.f - first);
        #pragma unroll
        for (int k = 0; k < NK; ++k) wts[(size_t)b * NK + k] = nw[k];
    }
}

// =====================================================================
extern "C" void kernel_launch(void* const* d_in, const int* in_sizes, int n_in,
                              void* d_out, int out_size, void* d_ws, size_t ws_size,
                              hipStream_t stream)
{
    (void)in_sizes; (void)n_in; (void)out_size; (void)ws_size;
    const float* context    = (const float*)d_in[0];
    const float* question   = (const float*)d_in[1];
    const float* knowledge  = (const float*)d_in[2];
    const float* kb_proj    = (const float*)d_in[3];
    const float* control0   = (const float*)d_in[4];
    const float* memory0    = (const float*)d_in[5];
    const float* history0   = (const float*)d_in[6];
    const float* wt0        = (const float*)d_in[7];
    const float* ctrl_pos_w = (const float*)d_in[8];
    const float* ctrl_pos_b = (const float*)d_in[9];
    const float* ctrl_cq_w  = (const float*)d_in[10];
    const float* ctrl_cq_b  = (const float*)d_in[11];
    const float* ctrl_attn_w= (const float*)d_in[12];
    const float* read_mem_w = (const float*)d_in[14];
    const float* read_mem_b = (const float*)d_in[15];
    const float* read_cat_w = (const float*)d_in[16];
    const float* read_attn_w= (const float*)d_in[18];
    const float* rm_mem_w   = (const float*)d_in[20];
    const float* rm_mem_b   = (const float*)d_in[21];
    const float* rm_cat_w   = (const float*)d_in[22];
    const float* rm_attn_w  = (const float*)d_in[24];
    const float* write_w    = (const float*)d_in[26];
    const float* write_b    = (const float*)d_in[27];
    const float* lr_w1      = (const float*)d_in[28];
    const float* lr_b1      = (const float*)d_in[29];
    const float* lr_w2      = (const float*)d_in[30];
    const float* lr_b2      = (const float*)d_in[31];
    const float* lrh_w1     = (const float*)d_in[32];
    const float* lrh_b1     = (const float*)d_in[33];
    const float* lrh_w2     = (const float*)d_in[34];
    const float* lrh_b2     = (const float*)d_in[35];
    const float* mix_w1     = (const float*)d_in[36];
    const float* mix_b1     = (const float*)d_in[37];
    const float* mix_w2     = (const float*)d_in[38];
    const float* mix_b2     = (const float*)d_in[39];

    // ---- workspace: floats then bf16 hi/lo shorts ----
    float* f = (float*)d_ws;
    auto takef = [&](size_t n) { float* p = f; f += n; return p; };
    float* pa_all = takef((size_t)NB * 2048);
    float* cqi    = takef((size_t)NB * ND);
    float* control= takef((size_t)NB * ND);
    float* cw     = takef((size_t)NB * ND);
    float* cwh    = takef((size_t)NB * ND);
    float* mpc    = takef((size_t)NB * 1024);   // [mem_p | memh]
    float* u      = takef((size_t)NB * 1024);
    float* uh     = takef((size_t)NB * 1024);
    float* readv  = takef((size_t)NB * ND);
    float* read_h = takef((size_t)NB * ND);
    float* rvi    = takef((size_t)NB * NK);
    float* g1a    = takef((size_t)NB * 1024);
    float* g1b    = takef((size_t)NB * 1024);
    float* m1buf  = takef((size_t)NB * ND);
    float* ctx    = takef((size_t)NB * ND);
    float* hist   = takef((size_t)NB * ND * NK);
    float* wts    = takef((size_t)NB * NK);
    float* memA   = takef((size_t)NB * ND);
    float* memB   = takef((size_t)NB * ND);
    float* s_part = takef((size_t)4 * NB * 200);
    float* bcat   = takef(1024);

    short* s = (short*)f;
    auto takes = [&](size_t n) { short* p = s; s += n; return p; };
    short* cpw_h = takes((size_t)2048 * 1024); short* cpw_l = takes((size_t)2048 * 1024);
    short* cqw_h = takes((size_t)512 * 1024);  short* cqw_l = takes((size_t)512 * 1024);
    short* wmc_h = takes((size_t)1024 * 512);  short* wmc_l = takes((size_t)1024 * 512);
    short* rcw_h = takes((size_t)1024 * 512);  short* rcw_l = takes((size_t)1024 * 512);
    short* rmw_h = takes((size_t)1024 * 512);  short* rmw_l = takes((size_t)1024 * 512);
    short* lrw_h = takes((size_t)1024 * 1024); short* lrw_l = takes((size_t)1024 * 1024);
    short* lhw_h = takes((size_t)1024 * 1024); short* lhw_l = takes((size_t)1024 * 1024);
    short* mxw_h = takes((size_t)512 * 512);   short* mxw_l = takes((size_t)512 * 512);
    short* ww_h  = takes((size_t)512 * 1024);  short* ww_l  = takes((size_t)512 * 1024);

    // ---- prologue: state copies + weight conversion ----
    hipMemcpyAsync(hist, history0, sizeof(float) * NB * ND * NK, hipMemcpyDeviceToDevice, stream);
    hipMemcpyAsync(wts,  wt0,      sizeof(float) * NB * NK,      hipMemcpyDeviceToDevice, stream);
    hipMemcpyAsync(bcat,       read_mem_b, sizeof(float) * 512, hipMemcpyDeviceToDevice, stream);
    hipMemcpyAsync(bcat + 512, rm_mem_b,   sizeof(float) * 512, hipMemcpyDeviceToDevice, stream);

    WTab tab;
    tab.s[0] = {ctrl_pos_w, cpw_h, cpw_l, 2048 * 1024};
    tab.s[1] = {ctrl_cq_w,  cqw_h, cqw_l, 512 * 1024};
    tab.s[2] = {read_mem_w, wmc_h, wmc_l, 512 * 512};
    tab.s[3] = {rm_mem_w,   wmc_h + 512 * 512, wmc_l + 512 * 512, 512 * 512};
    tab.s[4] = {lr_w1,  lrw_h, lrw_l, 1024 * 1024};
    tab.s[5] = {lrh_w1, lhw_h, lhw_l, 1024 * 1024};
    tab.s[6] = {mix_w1, mxw_h, mxw_l, 512 * 512};
    tab.s[7] = {write_w, ww_h, ww_l, 512 * 1024};
    tab.total = 2048*1024 + 512*1024 + 512*512 + 512*512 + 1024*1024 + 1024*1024 + 512*512 + 512*1024;
    wconv_k<<<dim3((tab.total + 255) / 256), dim3(256), 0, stream>>>(tab);
    tconv_k<<<dim3(32, 16, 2), dim3(256), 0, stream>>>(read_cat_w, rcw_h, rcw_l,
                                                       rm_cat_w,  rmw_h, rmw_l);

    auto P = [](const float* A1, const float* A2, int lda1, int lda2, int k1,
                const short* Bh, const short* Bl, const float* bias, float* C,
                int N, int K, int tile0) {
        GP q; q.A1 = A1; q.A2 = A2; q.Bh = Bh; q.Bl = Bl; q.bias = bias; q.C = C;
        q.lda1 = lda1; q.lda2 = lda2; q.k1 = k1; q.N = N; q.K = K;
        q.ntN = N / 64; q.tile0 = tile0;
        return q;
    };
    auto tilesOf = [](int N) { return (N / 64) * (NB / 32); };
    auto GG = [&](GP3 g, int total, int act) {
        if (act) ggemm_k<1><<<dim3(total), dim3(256), 0, stream>>>(g);
        else     ggemm_k<0><<<dim3(total), dim3(256), 0, stream>>>(g);
    };

    // pa for all 4 steps: (B,1024) @ ctrl_pos_w(2048,1024)^T — 512 tiles
    {
        GP3 g; g.np = 1;
        g.p[0] = P(question, question, 1024, 1024, 1024, cpw_h, cpw_l, ctrl_pos_b, pa_all, 2048, 1024, 0);
        GG(g, tilesOf(2048), 0);
    }

    // memory chain: step i reads mems[i], writes mems[i+1]
    const float* mems[5] = {memory0, memA, memB, memA, (float*)d_out};
    const float* ctrl_cur = control0;

    for (int i = 0; i < NSTEP; ++i) {
        // ---- A: {write_{i-1} (if any)} + {cqi_i} in one launch ----
        {
            GP3 g; int nt = 0, np = 0;
            if (i > 0) {
                g.p[np++] = P(ctx, mems[i - 1], ND, ND, ND, ww_h, ww_l, write_b,
                              (float*)mems[i], ND, 1024, nt);
                nt += tilesOf(ND);
            }
            g.p[np++] = P(ctrl_cur, pa_all + (size_t)i * ND, ND, 2048, ND,
                          cqw_h, cqw_l, ctrl_cq_b, cqi, ND, 1024, nt);
            nt += tilesOf(ND);
            g.np = np;
            GG(g, nt, 0);
        }
        // ---- B: control attention ----
        ctrl_attn_k<<<dim3(NB), dim3(512), 0, stream>>>(cqi, context, ctrl_attn_w,
                                                        read_attn_w, rm_attn_w, control, cw, cwh);
        ctrl_cur = control;
        // ---- C: {mpc, u, uh} ----
        {
            GP3 g; g.np = 3;
            g.p[0] = P(mems[i], mems[i], ND, ND, ND, wmc_h, wmc_l, bcat, mpc, 1024, 512, 0);
            g.p[1] = P(cw,  cw,  ND, ND, ND, rcw_h, rcw_l, nullptr, u,  1024, 512, 256);
            g.p[2] = P(cwh, cwh, ND, ND, ND, rmw_h, rmw_l, nullptr, uh, 1024, 512, 512);
            GG(g, 768, 0);
        }
        // ---- D: kb scores + history attention (merged) ----
        kbsh_k<<<dim3(5 * NB), dim3(256), 0, stream>>>(kb_proj, mpc, u, s_part,
                                                       hist, uh, rvi, read_h);
        // ---- E: kb softmax + read ----
        kb_read_k<<<dim3(8, NB), dim3(256), 0, stream>>>(knowledge, s_part, readv);
        // ---- F: {g1a, g1b, m1} (all ELU) ----
        {
            GP3 g; g.np = 3;
            g.p[0] = P(control, readv,  ND, ND, ND, lrw_h, lrw_l, lr_b1,  g1a, 1024, 1024, 0);
            g.p[1] = P(control, read_h, ND, ND, ND, lhw_h, lhw_l, lrh_b1, g1b, 1024, 1024, 256);
            g.p[2] = P(control, control, ND, ND, ND, mxw_h, mxw_l, mix_b1, m1buf, 512, 512, 512);
            GG(g, 640, 1);
        }
        // ---- G: scalars + state update ----
        update2_k<<<dim3(NB), dim3(256), 0, stream>>>(g1a, g1b, m1buf,
                                                      lr_w2, lr_b2, lrh_w2, lrh_b2,
                                                      mix_w2, mix_b2, rvi, readv, read_h,
                                                      hist, wts, ctx);
    }
    // ---- final write: memory_4 -> d_out ----
    {
        GP3 g; g.np = 1;
        g.p[0] = P(ctx, mems[3], ND, ND, ND, ww_h, ww_l, write_b, (float*)mems[4], ND, 1024, 0);
        GG(g, tilesOf(ND), 0);
    }
}